// Round 1
// baseline (155.436 us; speedup 1.0000x reference)
//
#include <hip/hip_runtime.h>
#include <hip/hip_cooperative_groups.h>

namespace cg = cooperative_groups;

// DeterministicEncoder: MLP encoder [M,2]->[M,64] + Laplace-kernel attention.
// exp(-|k-q|) factorizes: with context sorted by key, exclusive-prefix
// Lo[j] = sum_{i<j} e^{s_i} v_i and suffix Hi[j] = sum_{i>=j} e^{-s_i} v_i give
// out[n] = e^{-q} Lo[j_n] + e^{q} Hi[j_n], j_n = lower_bound(skey, q).
//
// Round 9: kill K2's redundancy. Old K2 (64 ch x 4 quarters) re-staged and
// re-scanned each channel 4x and ran 524288 binary searches when only 8192
// exist (j_n is channel-independent). New: ONE cooperative kernel.
//   Phase B (blocks 0..127): each (channel, Lo/Hi) scan computed once, stored
//     TRANSPOSED LoT[j][c]/HiT[j][c] so phase C reads coalesced 256B rows.
//   grid.sync()
//   Phase C (all 256 blocks): wave-per-target (lane = channel): one
//     wave-uniform 13-step LDS search per target, 2 coalesced row gathers,
//     coalesced 256B out-row store. LDS 134KB -> 33KB.
// FP op order of the scans is identical to the verified round-8 kernel.

#define H    16
#define OUTD 64
#define MM   8192                 // context/target count, fixed by harness
#define PAD(i) ((i) + ((i) >> 5)) // LDS bank padding

// ---------------------------------------------------------------- K1
// 256 blocks x 1024. Block b: rank+scatter rows [32b,32b+32), MLP same rows.
// (unchanged from round 8 — verified)
__global__ __launch_bounds__(1024) void rank_mlp_kernel(
    const float* __restrict__ xc, const float* __restrict__ yc,
    const float* __restrict__ W1, const float* __restrict__ b1,
    const float* __restrict__ W2, const float* __restrict__ b2,
    const float* __restrict__ W3, const float* __restrict__ b3,
    float* __restrict__ vT, float* __restrict__ skey, int* __restrict__ perm)
{
    __shared__ float sk[MM];          // all keys, 32 KB
    __shared__ int   red[32][4];      // [row][key-quarter] partial ranks
    __shared__ float sh2[32][H + 1];  // h2 per row, padded (17: coprime to 32)
    const int t = threadIdx.x;
    const int b = blockIdx.x;
    const int lane = t & 63, wid = t >> 6;

    for (int i = t; i < MM / 4; i += 1024)        // coalesced 16B staging
        ((float4*)sk)[i] = ((const float4*)xc)[i];
    __syncthreads();

    // rank: wave wid -> row-group rg = wid>>2 (8 rows), key-quarter qt = wid&3.
    {
        const int rg = wid >> 2, qt = wid & 3;
        const int m0 = b * 32 + rg * 8;
        float mk[8];
#pragma unroll
        for (int j = 0; j < 8; j++) mk[j] = sk[m0 + j];   // wave-uniform reads
        int cnt[8] = {0, 0, 0, 0, 0, 0, 0, 0};
#pragma unroll
        for (int ch = 0; ch < 8; ch++) {
            const int g = qt * 2048 + ch * 256 + lane * 4;
            const float4 k4 = *(const float4*)(sk + g);
#pragma unroll
            for (int j = 0; j < 8; j++) {
                const int m = m0 + j;
                const float k = mk[j];
                // strict total order on (key, index) -> rank is a permutation
                cnt[j] += (k4.x < k || (k4.x == k && (g + 0) < m)) ? 1 : 0;
                cnt[j] += (k4.y < k || (k4.y == k && (g + 1) < m)) ? 1 : 0;
                cnt[j] += (k4.z < k || (k4.z == k && (g + 2) < m)) ? 1 : 0;
                cnt[j] += (k4.w < k || (k4.w == k && (g + 3) < m)) ? 1 : 0;
            }
        }
#pragma unroll
        for (int j = 0; j < 8; j++) {            // in-wave reduction
            int v = cnt[j];
#pragma unroll
            for (int off = 32; off; off >>= 1) v += __shfl_down(v, off);
            if (lane == 0) red[rg * 8 + j][qt] = v;
        }
    }

    // MLP stage 1: h2 once per row (t<32).
    if (t < 32) {
        const int m = b * 32 + t;
        const float x = sk[m], y = yc[m];
        float h1[H];
#pragma unroll
        for (int j = 0; j < H; j++) {
            float a = x * W1[j] + y * W1[H + j] + b1[j];
            h1[j] = a > 0.f ? a : 0.f;
        }
#pragma unroll
        for (int j = 0; j < H; j++) {
            float a = b2[j];
#pragma unroll
            for (int i = 0; i < H; i++) a += h1[i] * W2[i * H + j];
            sh2[t][j] = a > 0.f ? a : 0.f;
        }
    }
    __syncthreads();

    // scatter (t<32) -- 4-elem sum of partials, then direct sorted write.
    if (t < 32) {
        const int m = b * 32 + t;
        const int r = red[t][0] + red[t][1] + red[t][2] + red[t][3];
        skey[r] = sk[m];
        perm[r] = m;
    }

    // MLP stage 2: ml = t&31 (lane-fast ROW) -> coalesced vT stores.
    {
        const int ml = t & 31, chp = t >> 5;
        const int m = b * 32 + ml;
        const int cb = chp * 2;
        float a0 = b3[cb], a1 = b3[cb + 1];
#pragma unroll
        for (int i = 0; i < H; i++) {
            const float h = sh2[ml][i];
            const float2 w2 = ((const float2*)(W3 + i * OUTD))[chp];
            a0 += h * w2.x;
            a1 += h * w2.y;
        }
        vT[(size_t)cb * MM + m]       = a0;
        vT[(size_t)(cb + 1) * MM + m] = a1;
    }
}

// ---------------------------------------------------------------- K2 (coop)
// 256 blocks x 1024, cooperative launch.
// Phase B: blocks 0..127 = (channel c = bid&63, doHi = bid>>6). Scan once,
//          write transposed LoT/HiT rows [j][c] (+ boundary row j=MM).
// Phase C: all 256 blocks: block b answers targets [32b, 32b+32), one wave
//          per 2 targets (searches interleaved for ILP), lane = channel.
__global__ __launch_bounds__(1024) void scan_query_coop(
    const float* __restrict__ xt, const float* __restrict__ skey,
    const int* __restrict__ perm, const float* __restrict__ vT,
    float* __restrict__ LoT, float* __restrict__ HiT,
    float* __restrict__ out)
{
    __shared__ float sbuf[PAD(MM) + 1];  // phase B: value row; phase C: padded keys
    __shared__ float ws16[16];           // per-wave scan totals
    const int t = threadIdx.x;
    const int lane = t & 63, wid = t >> 6;
    const int bid = blockIdx.x;

    // ---- phase B: one scan per (channel, direction) ----
    if (bid < 2 * OUTD) {
        const int c    = bid & (OUTD - 1);
        const int doHi = bid >> 6;
        const float* __restrict__ vrow = vT + (size_t)c * MM;

        for (int i = t; i < MM / 4; i += 1024)   // coalesced 16B staging
            ((float4*)sbuf)[i] = ((const float4*)vrow)[i];
        __syncthreads();

        const int base = t * 8;
        float vv[8], ks[8];
        {
            const int4* pp = (const int4*)(perm + base);
            const int4 p0 = pp[0], p1 = pp[1];
            vv[0] = sbuf[p0.x]; vv[1] = sbuf[p0.y];
            vv[2] = sbuf[p0.z]; vv[3] = sbuf[p0.w];
            vv[4] = sbuf[p1.x]; vv[5] = sbuf[p1.y];
            vv[6] = sbuf[p1.z]; vv[7] = sbuf[p1.w];
        }
        {
            const float4* kk = (const float4*)(skey + base);  // coalesced, L2-hot
            const float4 k0 = kk[0], k1 = kk[1];
            ks[0] = k0.x; ks[1] = k0.y; ks[2] = k0.z; ks[3] = k0.w;
            ks[4] = k1.x; ks[5] = k1.y; ks[6] = k1.z; ks[7] = k1.w;
        }

        if (!doHi) {
            // Lo: exclusive prefix of e^{s} v  (same FP order as round 8)
            float w[8], S = 0.f;
#pragma unroll
            for (int r = 0; r < 8; r++) { w[r] = __expf(ks[r]) * vv[r]; S += w[r]; }
            float inc = S;
#pragma unroll
            for (int off = 1; off < 64; off <<= 1) {
                float a = __shfl_up(inc, (unsigned)off);
                if (lane >= off) inc += a;
            }
            if (lane == 63) ws16[wid] = inc;
            __syncthreads();
            float before = 0.f;
#pragma unroll
            for (int ww = 0; ww < 16; ww++) before += (ww < wid) ? ws16[ww] : 0.f;
            float run = before + inc - S;
#pragma unroll
            for (int r = 0; r < 8; r++) {
                LoT[(size_t)(base + r) * OUTD + c] = run;
                run += w[r];
            }
            if (t == 1023) LoT[(size_t)MM * OUTD + c] = run;
        } else {
            // Hi: suffix of e^{-s} v
            float w[8], S2 = 0.f;
#pragma unroll
            for (int r = 0; r < 8; r++) { w[r] = __expf(-ks[r]) * vv[r]; S2 += w[r]; }
            float inc2 = S2;
#pragma unroll
            for (int off = 1; off < 64; off <<= 1) {
                float a = __shfl_down(inc2, (unsigned)off);
                if (lane + off < 64) inc2 += a;
            }
            if (lane == 0) ws16[wid] = inc2;
            __syncthreads();
            float after = 0.f;
#pragma unroll
            for (int ww = 0; ww < 16; ww++) after += (ww > wid) ? ws16[ww] : 0.f;
            float run2 = after + inc2 - S2;
#pragma unroll
            for (int r = 7; r >= 0; r--) {
                run2 += w[r];
                HiT[(size_t)(base + r) * OUTD + c] = run2;
            }
            if (t == 0) HiT[(size_t)MM * OUTD + c] = 0.f;
        }
    }

    cg::this_grid().sync();   // LoT/HiT complete + visible device-wide

    // ---- phase C: wave-per-target query, lane = channel ----
    for (int i = t; i < MM / 4; i += 1024) {     // stage padded sorted keys
        const float4 k4 = ((const float4*)skey)[i];
        sbuf[PAD(4 * i + 0)] = k4.x; sbuf[PAD(4 * i + 1)] = k4.y;
        sbuf[PAD(4 * i + 2)] = k4.z; sbuf[PAD(4 * i + 3)] = k4.w;
    }
    __syncthreads();

    const int n0 = bid * 32 + wid * 2;   // two targets per wave
    const int n1 = n0 + 1;
    const float q0 = xt[n0], q1 = xt[n1];        // wave-uniform broadcast loads
    int lo0 = 0, hi0v = MM, lo1 = 0, hi1v = MM;
#pragma unroll
    for (int s = 0; s < 13; s++) {       // 8192 = 2^13: exactly 13 steps
        const int mid0 = (lo0 + hi0v) >> 1;
        const int mid1 = (lo1 + hi1v) >> 1;
        if (sbuf[PAD(mid0)] < q0) lo0 = mid0 + 1; else hi0v = mid0;
        if (sbuf[PAD(mid1)] < q1) lo1 = mid1 + 1; else hi1v = mid1;
    }
    // coalesced 256B row gathers (lo is wave-uniform) + coalesced row stores
    const float l0 = LoT[(size_t)lo0 * OUTD + lane];
    const float h0 = HiT[(size_t)lo0 * OUTD + lane];
    const float l1 = LoT[(size_t)lo1 * OUTD + lane];
    const float h1 = HiT[(size_t)lo1 * OUTD + lane];
    out[(size_t)n0 * OUTD + lane] = __expf(-q0) * l0 + __expf(q0) * h0;
    out[(size_t)n1 * OUTD + lane] = __expf(-q1) * l1 + __expf(q1) * h1;
}

extern "C" void kernel_launch(void* const* d_in, const int* in_sizes, int n_in,
                              void* d_out, int out_size, void* d_ws, size_t ws_size,
                              hipStream_t stream)
{
    const float* xc = (const float*)d_in[0];
    const float* yc = (const float*)d_in[1];
    const float* xt = (const float*)d_in[2];
    const float* W1 = (const float*)d_in[3];
    const float* b1 = (const float*)d_in[4];
    const float* W2 = (const float*)d_in[5];
    const float* b2 = (const float*)d_in[6];
    const float* W3 = (const float*)d_in[7];
    const float* b3 = (const float*)d_in[8];
    float* out = (float*)d_out;

    // workspace: vT [64][MM] (2MB) | skey [MM] | perm [MM]
    //          | LoT [(MM+1)][64] (2MB) | HiT [(MM+1)][64] (2MB)   (~6.2MB total)
    char* ws = (char*)d_ws;
    float* vT   = (float*)ws;
    float* skey = (float*)(ws + (size_t)OUTD * MM * 4);
    int*   perm = (int*)  (ws + (size_t)OUTD * MM * 4 + (size_t)MM * 4);
    float* LoT  = (float*)(ws + (size_t)OUTD * MM * 4 + (size_t)MM * 8);
    float* HiT  = LoT + (size_t)(MM + 1) * OUTD;

    rank_mlp_kernel<<<256, 1024, 0, stream>>>(xc, yc, W1, b1, W2, b2, W3, b3,
                                              vT, skey, perm);

    void* args[] = {(void*)&xt, (void*)&skey, (void*)&perm, (void*)&vT,
                    (void*)&LoT, (void*)&HiT, (void*)&out};
    hipLaunchCooperativeKernel((const void*)scan_query_coop, dim3(256),
                               dim3(1024), args, 0, stream);
}

// Round 3
// 95.966 us; speedup vs baseline: 1.6197x; 1.6197x over previous
//
#include <hip/hip_runtime.h>

// DeterministicEncoder: MLP encoder [M,2]->[M,64] + Laplace-kernel attention.
// exp(-|k-q|) factorizes: with context sorted by key, exclusive-prefix
// Lo[j] = sum_{i<j} e^{s_i} v_i and suffix Hi[j] = sum_{i>=j} e^{-s_i} v_i give
// out[n] = e^{-q} Lo[j_n] + e^{q} Hi[j_n], j_n = lower_bound(skey, q).
//
// Round 11: fix round-10's single correctness bug. The Hi-side combine used
// tpHiA[t0] (tiles >= t0) AND HiT[lo0] (within-tile-t0 suffix) -> tile t0
// counted twice. Correct cross-tile term is tpHiA[t0+1] (tiles strictly
// after t0). Lo side was already correct. Structure otherwise unchanged:
//  - 3 plain stream-ordered kernels (no cooperative launch: round 9 showed
//    ~+50us non-kernel overhead).
//  - no scattered 4B column writes (round 9: WRITE_SIZE 34.8MB vs 6MB
//    logical from cross-XCD false sharing on 256B-strided stores). All
//    global arrays written as one 256B row per wave (lane = channel).

#define H     16
#define OUTD  64
#define MM    8192                 // context/target count, fixed by harness
#define PAD(i) ((i) + ((i) >> 5)) // LDS bank padding
#define TILES 64
#define TROWS 128                  // rows per scan tile
#define RPT   8                    // rows per thread in K2a (16 rg * 8 = 128)

// ---------------------------------------------------------------- K1
// 256 blocks x 1024. Block b: rank+scatter rows [32b,32b+32), MLP same rows.
// Rank section unchanged (verified). Values stored SORTED row-major.
__global__ __launch_bounds__(1024) void rank_mlp_kernel(
    const float* __restrict__ xc, const float* __restrict__ yc,
    const float* __restrict__ W1, const float* __restrict__ b1,
    const float* __restrict__ W2, const float* __restrict__ b2,
    const float* __restrict__ W3, const float* __restrict__ b3,
    float* __restrict__ vS, float* __restrict__ skey)
{
    __shared__ float sk[MM];          // all keys, 32 KB
    __shared__ int   red[32][4];      // [row][key-quarter] partial ranks
    __shared__ float sh2[32][H + 1];  // h2 per row, padded (17: coprime to 32)
    __shared__ int   rrk[32];         // rank of each of this block's 32 rows
    const int t = threadIdx.x;
    const int b = blockIdx.x;
    const int lane = t & 63, wid = t >> 6;

    for (int i = t; i < MM / 4; i += 1024)        // coalesced 16B staging
        ((float4*)sk)[i] = ((const float4*)xc)[i];
    __syncthreads();

    // rank: wave wid -> row-group rg = wid>>2 (8 rows), key-quarter qt = wid&3.
    {
        const int rg = wid >> 2, qt = wid & 3;
        const int m0 = b * 32 + rg * 8;
        float mk[8];
#pragma unroll
        for (int j = 0; j < 8; j++) mk[j] = sk[m0 + j];   // wave-uniform reads
        int cnt[8] = {0, 0, 0, 0, 0, 0, 0, 0};
#pragma unroll
        for (int ch = 0; ch < 8; ch++) {
            const int g = qt * 2048 + ch * 256 + lane * 4;
            const float4 k4 = *(const float4*)(sk + g);
#pragma unroll
            for (int j = 0; j < 8; j++) {
                const int m = m0 + j;
                const float k = mk[j];
                // strict total order on (key, index) -> rank is a permutation
                cnt[j] += (k4.x < k || (k4.x == k && (g + 0) < m)) ? 1 : 0;
                cnt[j] += (k4.y < k || (k4.y == k && (g + 1) < m)) ? 1 : 0;
                cnt[j] += (k4.z < k || (k4.z == k && (g + 2) < m)) ? 1 : 0;
                cnt[j] += (k4.w < k || (k4.w == k && (g + 3) < m)) ? 1 : 0;
            }
        }
#pragma unroll
        for (int j = 0; j < 8; j++) {            // in-wave reduction
            int v = cnt[j];
#pragma unroll
            for (int off = 32; off; off >>= 1) v += __shfl_down(v, off);
            if (lane == 0) red[rg * 8 + j][qt] = v;
        }
    }

    // MLP stage 1: h2 once per row (t<32).
    if (t < 32) {
        const int m = b * 32 + t;
        const float x = sk[m], y = yc[m];
        float h1[H];
#pragma unroll
        for (int j = 0; j < H; j++) {
            float a = x * W1[j] + y * W1[H + j] + b1[j];
            h1[j] = a > 0.f ? a : 0.f;
        }
#pragma unroll
        for (int j = 0; j < H; j++) {
            float a = b2[j];
#pragma unroll
            for (int i = 0; i < H; i++) a += h1[i] * W2[i * H + j];
            sh2[t][j] = a > 0.f ? a : 0.f;
        }
    }
    __syncthreads();

    // scatter (t<32): rank = sum of 4 partials, write sorted key + publish rank
    if (t < 32) {
        const int m = b * 32 + t;
        const int r = red[t][0] + red[t][1] + red[t][2] + red[t][3];
        skey[r] = sk[m];
        rrk[t] = r;
    }
    __syncthreads();   // stage 2 needs rrk

    // MLP stage 2: chp = t&31 lane-fast -> each half-wave writes one 256B
    // contiguous row vS[r][0..63] (float2 per lane). No false sharing: rows
    // are 256B-aligned and rank is a permutation (single writer per row).
    {
        const int chp = t & 31, ml = t >> 5;
        const int r = rrk[ml];
        const int cb = chp * 2;
        float a0 = b3[cb], a1 = b3[cb + 1];
#pragma unroll
        for (int i = 0; i < H; i++) {
            const float h = sh2[ml][i];          // half-wave-uniform broadcast
            const float2 w2 = ((const float2*)(W3 + i * OUTD))[chp];
            a0 += h * w2.x;
            a1 += h * w2.y;
        }
        ((float2*)(vS + (size_t)r * OUTD))[chp] = make_float2(a0, a1);
    }
}

// ---------------------------------------------------------------- K2a (scan)
// 64 blocks x 1024. Block = one 128-row tile x ALL 64 channels.
// Thread (c = t&63, rg = t>>6) accumulates 8 rows serially; block-level LDS
// scan over the 16 row-groups; writes WITHIN-TILE exclusive prefix LoT[j][c]
// and suffix HiT[j][c] as coalesced 256B rows, plus per-tile totals.
__global__ __launch_bounds__(1024) void scan_kernel(
    const float* __restrict__ skey, const float* __restrict__ vS,
    float* __restrict__ LoT, float* __restrict__ HiT,
    float* __restrict__ tileLo, float* __restrict__ tileHi)
{
    __shared__ float ldsLo[16][OUTD];
    __shared__ float ldsHi[16][OUTD];
    const int t = threadIdx.x;
    const int c = t & 63, rg = t >> 6;
    const int tile = blockIdx.x;
    const int i0 = tile * TROWS + rg * RPT;

    float wLo[RPT], wHi[RPT];
    float sLo = 0.f, sHi = 0.f;
#pragma unroll
    for (int r = 0; r < RPT; r++) {
        const int i = i0 + r;
        const float k = skey[i];                 // wave-uniform broadcast load
        const float v = vS[(size_t)i * OUTD + c]; // coalesced 256B row
        const float eP = __expf(k), eN = __expf(-k);
        wLo[r] = eP * v;
        wHi[r] = eN * v;
        sLo += wLo[r];
        sHi += wHi[r];
    }
    ldsLo[rg][c] = sLo;
    ldsHi[rg][c] = sHi;
    __syncthreads();

    float preLo = 0.f, sufHi = 0.f;              // tile-local scan offsets
#pragma unroll
    for (int g = 0; g < 16; g++) {
        const float a = ldsLo[g][c];
        const float bb = ldsHi[g][c];
        preLo += (g < rg) ? a : 0.f;
        sufHi += (g > rg) ? bb : 0.f;
    }

    float run = preLo;                           // exclusive prefix (Lo)
#pragma unroll
    for (int r = 0; r < RPT; r++) {
        LoT[(size_t)(i0 + r) * OUTD + c] = run;  // coalesced 256B row
        run += wLo[r];
    }
    float run2 = sufHi;                          // inclusive suffix (Hi)
#pragma unroll
    for (int r = RPT - 1; r >= 0; r--) {
        run2 += wHi[r];
        HiT[(size_t)(i0 + r) * OUTD + c] = run2; // coalesced 256B row
    }

    if (rg == 15) tileLo[tile * OUTD + c] = preLo + sLo;  // tile total
    if (rg == 0)  tileHi[tile * OUTD + c] = sufHi + sHi;  // tile total
}

// ---------------------------------------------------------------- K2b (query)
// 256 blocks x 1024. Block b answers targets [32b, 32b+32), one wave per 2
// targets (interleaved searches), lane = channel. Cross-tile prefixes built
// once per block in LDS. All global reads/writes are coalesced 256B rows.
__global__ __launch_bounds__(1024) void query_kernel(
    const float* __restrict__ xt, const float* __restrict__ skey,
    const float* __restrict__ LoT, const float* __restrict__ HiT,
    const float* __restrict__ tileLo, const float* __restrict__ tileHi,
    float* __restrict__ out)
{
    __shared__ float sk[PAD(MM) + 1];            // padded sorted keys, ~33KB
    __shared__ float tpLo [TILES + 1][OUTD];     // sum_{t'<t}  tileLo, 16.6KB
    __shared__ float tpHiA[TILES + 1][OUTD];     // sum_{t'>=t} tileHi, 16.6KB
    const int t = threadIdx.x;
    const int lane = t & 63, wid = t >> 6;
    const int bid = blockIdx.x;

    for (int i = t; i < MM / 4; i += 1024) {     // stage padded sorted keys
        const float4 k4 = ((const float4*)skey)[i];
        sk[PAD(4 * i + 0)] = k4.x; sk[PAD(4 * i + 1)] = k4.y;
        sk[PAD(4 * i + 2)] = k4.z; sk[PAD(4 * i + 3)] = k4.w;
    }
    if (t < OUTD) {                              // per-channel tile prefixes
        float acc = 0.f;
        tpLo[0][t] = 0.f;
#pragma unroll 8
        for (int tt = 0; tt < TILES; tt++) {     // coalesced per step
            acc += tileLo[tt * OUTD + t];
            tpLo[tt + 1][t] = acc;
        }
        float acc2 = 0.f;
        tpHiA[TILES][t] = 0.f;
#pragma unroll 8
        for (int tt = TILES - 1; tt >= 0; tt--) {
            acc2 += tileHi[tt * OUTD + t];
            tpHiA[tt][t] = acc2;
        }
    }
    __syncthreads();

    // two interleaved wave-uniform 13-step lower_bounds (broadcast LDS reads)
    const int n0 = bid * 32 + wid * 2;
    const int n1 = n0 + 1;
    const float q0 = xt[n0], q1 = xt[n1];        // wave-uniform broadcasts
    int lo0 = 0, hi0v = MM, lo1 = 0, hi1v = MM;
#pragma unroll
    for (int s = 0; s < 13; s++) {               // 8192 = 2^13: exactly 13
        const int mid0 = (lo0 + hi0v) >> 1;
        const int mid1 = (lo1 + hi1v) >> 1;
        if (sk[PAD(mid0)] < q0) lo0 = mid0 + 1; else hi0v = mid0;
        if (sk[PAD(mid1)] < q1) lo1 = mid1 + 1; else hi1v = mid1;
    }

    // combine: Lo = tiles-before prefix + within-tile exclusive prefix;
    //          Hi = tiles-AFTER suffix (tpHiA[t0+1]!) + within-tile suffix.
    // (round-10 bug: used tpHiA[t0], double-counting tile t0.)
    const int t0 = lo0 >> 7, t1 = lo1 >> 7;      // tile index (lo==MM -> 64)
    float L0 = tpLo[t0][lane], Hh0;
    float L1 = tpLo[t1][lane], Hh1;
    if (lo0 < MM) {                              // wave-uniform branch
        L0  += LoT[(size_t)lo0 * OUTD + lane];
        Hh0  = tpHiA[t0 + 1][lane] + HiT[(size_t)lo0 * OUTD + lane];
    } else {
        Hh0 = 0.f;                               // lo0 == MM: nothing above
    }
    if (lo1 < MM) {
        L1  += LoT[(size_t)lo1 * OUTD + lane];
        Hh1  = tpHiA[t1 + 1][lane] + HiT[(size_t)lo1 * OUTD + lane];
    } else {
        Hh1 = 0.f;
    }
    out[(size_t)n0 * OUTD + lane] = __expf(-q0) * L0 + __expf(q0) * Hh0;
    out[(size_t)n1 * OUTD + lane] = __expf(-q1) * L1 + __expf(q1) * Hh1;
}

extern "C" void kernel_launch(void* const* d_in, const int* in_sizes, int n_in,
                              void* d_out, int out_size, void* d_ws, size_t ws_size,
                              hipStream_t stream)
{
    const float* xc = (const float*)d_in[0];
    const float* yc = (const float*)d_in[1];
    const float* xt = (const float*)d_in[2];
    const float* W1 = (const float*)d_in[3];
    const float* b1 = (const float*)d_in[4];
    const float* W2 = (const float*)d_in[5];
    const float* b2 = (const float*)d_in[6];
    const float* W3 = (const float*)d_in[7];
    const float* b3 = (const float*)d_in[8];
    float* out = (float*)d_out;

    // workspace: vS [MM][64] (2MB) | skey [MM] (32KB) | LoT [MM][64] (2MB)
    //          | HiT [MM][64] (2MB) | tileLo [64][64] | tileHi [64][64]
    char* ws = (char*)d_ws;
    float* vS     = (float*)ws;
    float* skey   = (float*)(ws + (size_t)MM * OUTD * 4);
    float* LoT    = (float*)(ws + (size_t)MM * OUTD * 4 + (size_t)MM * 4);
    float* HiT    = LoT + (size_t)MM * OUTD;
    float* tileLo = HiT + (size_t)MM * OUTD;
    float* tileHi = tileLo + TILES * OUTD;

    rank_mlp_kernel<<<256, 1024, 0, stream>>>(xc, yc, W1, b1, W2, b2, W3, b3,
                                              vS, skey);
    scan_kernel<<<TILES, 1024, 0, stream>>>(skey, vS, LoT, HiT, tileLo, tileHi);
    query_kernel<<<256, 1024, 0, stream>>>(xt, skey, LoT, HiT, tileLo, tileHi,
                                           out);
}